// Round 3
// baseline (2509.515 us; speedup 1.0000x reference)
//
#include <hip/hip_runtime.h>

#define N_NODES 50000
#define N_EDGES 400000

typedef __bf16 bf16x8 __attribute__((ext_vector_type(8)));
typedef float f32x4 __attribute__((ext_vector_type(4)));

__device__ __forceinline__ float bflo(uint u){ union{uint i; float f;} v; v.i = u<<16; return v.f; }
__device__ __forceinline__ float bfhi(uint u){ union{uint i; float f;} v; v.i = u & 0xffff0000u; return v.f; }
__device__ __forceinline__ float bf2f(ushort u){ union{uint i; float f;} v; v.i = ((uint)u)<<16; return v.f; }
__device__ __forceinline__ ushort f2bf(float f){
  union{float f; uint i;} v; v.f = f;
  uint r = (v.i + 0x7fffu + ((v.i>>16)&1u))>>16;
  return (ushort)r;
}
__device__ __forceinline__ uint pack2(float a, float b){
  return (uint)f2bf(a) | ((uint)f2bf(b)<<16);
}

// ---------------- f32 -> bf16 convert ------------------------------------------
__global__ __launch_bounds__(256) void f32_to_bf16(
    const float* __restrict__ in, ushort* __restrict__ out, int n)
{
  int i = blockIdx.x*256 + threadIdx.x;
  if (i < n) out[i] = f2bf(in[i]);
}

// ---------------- LayerNorm: one wave per node, 2 channels/lane ----------------
__global__ __launch_bounds__(256) void ln_kernel(
    const float* __restrict__ x, const float* __restrict__ w,
    const float* __restrict__ b, ushort* __restrict__ xn)
{
  int n = blockIdx.x*4 + (threadIdx.x>>6);
  if (n >= N_NODES) return;
  int lane = threadIdx.x & 63;
  float2 xp = ((const float2*)x)[(size_t)n*64 + lane];
  float x0 = xp.x, x1 = xp.y;
  float s = x0 + x1, s2 = x0*x0 + x1*x1;
  #pragma unroll
  for (int off=1; off<64; off<<=1){ s += __shfl_xor(s,off); s2 += __shfl_xor(s2,off); }
  float mu  = s*(1.0f/128.0f);
  float var = s2*(1.0f/128.0f) - mu*mu;
  float inv = 1.0f/sqrtf(var + 1e-5f);
  float2 wp = ((const float2*)w)[lane];
  float2 bp = ((const float2*)b)[lane];
  float y0 = (x0-mu)*inv*wp.x + bp.x;
  float y1 = (x1-mu)*inv*wp.y + bp.y;
  ((uint*)xn)[(size_t)n*64 + lane] = pack2(y0, y1);
}

// ---------------- Generic MFMA GEMM: act(A[M,K] @ W[Nc,K]^T + bias) ------------
// 128x128 tile, BK=32, 4 waves, each wave 64x64 (4x4 frags of 16x16x32 bf16).
// AF32: A operand is f32 in global, converted to bf16 during LDS staging.
// Epilogue MODEs:
//  0: bf16 store          1: silu -> bf16 store
//  4: auxf2[row*Nc+c] *= vv                  (in-place vdot *= o2)
//  5: Cf[row*Nc+c] = aux1f[row*Nc+c] + vv    (dx = vdot + o3; Cf may alias aux1f)
//  6: Cf[row*Nc+c] = vv*bf16(aux1)[(row/3)*Nc+c] + aux2f[row*Nc+c]  (dvec)
//  7: dual-B: atomicAdd(aux2f[(row/3)*Nc+c], (acc1+b1)*(acc2+b2))   (vec_dot)
#define LDP 40  // padded LDS row (bf16 elems)

template<int MODE, int AF32>
__global__ __launch_bounds__(256) void gemm_bt(
    const void* __restrict__ Av, const ushort* __restrict__ W,
    const ushort* __restrict__ W2,
    const float* __restrict__ bias, const float* __restrict__ bias2,
    void* Cptr, const void* aux1, void* aux2,
    int M, int K, int Nc)
{
  __shared__ ushort As[128*LDP];
  __shared__ ushort Bs[128*LDP];
  __shared__ ushort Bs2[(MODE==7) ? 128*LDP : 2];
  const int tid = threadIdx.x;
  const int row0 = blockIdx.x*128, col0 = blockIdx.y*128;
  const int wave = tid>>6, lane = tid&63;
  const int wm = (wave>>1)*64, wn = (wave&1)*64;
  const int lr = lane&15, lq = lane>>4;
  f32x4 acc[4][4] = {};
  f32x4 acc2[4][4] = {};   // only used when MODE==7

  for (int k0=0; k0<K; k0+=32){
    #pragma unroll
    for (int rnd=0; rnd<2; rnd++){
      int e4 = (rnd*256 + tid)*8;
      int r = e4>>5, c = e4&31;
      int gk = k0 + c;
      { // A tile
        int gr = row0 + r;
        uint2 lo, hi;
        if (AF32){
          const float* Af = (const float*)Av;
          if (gr < M && gk + 8 <= K){
            const float* p = Af + (size_t)gr*K + gk;
            float4 f0 = *(const float4*)p;
            float4 f1 = *(const float4*)(p+4);
            lo = make_uint2(pack2(f0.x,f0.y), pack2(f0.z,f0.w));
            hi = make_uint2(pack2(f1.x,f1.y), pack2(f1.z,f1.w));
          } else {
            float t[8];
            #pragma unroll
            for (int i=0;i<8;i++) t[i] = (gr<M && gk+i<K) ? Af[(size_t)gr*K + gk + i] : 0.0f;
            lo = make_uint2(pack2(t[0],t[1]), pack2(t[2],t[3]));
            hi = make_uint2(pack2(t[4],t[5]), pack2(t[6],t[7]));
          }
        } else {
          const ushort* Ab = (const ushort*)Av;
          if (gr < M && gk + 8 <= K){
            const ushort* p = Ab + (size_t)gr*K + gk;
            lo = *(const uint2*)p; hi = *(const uint2*)(p+4);
          } else {
            ushort t[8];
            #pragma unroll
            for (int i=0;i<8;i++) t[i] = (gr<M && gk+i<K) ? Ab[(size_t)gr*K + gk + i] : (ushort)0;
            lo = make_uint2(((uint)t[0])|((uint)t[1]<<16), ((uint)t[2])|((uint)t[3]<<16));
            hi = make_uint2(((uint)t[4])|((uint)t[5]<<16), ((uint)t[6])|((uint)t[7]<<16));
          }
        }
        *(uint2*)&As[r*LDP + c]     = lo;
        *(uint2*)&As[r*LDP + c + 4] = hi;
      }
      { // B tile (W rows = output channels), bf16 pre-converted
        int gr = col0 + r;
        uint2 lo, hi;
        if (gr < Nc && gk + 8 <= K){
          const ushort* p = W + (size_t)gr*K + gk;
          lo = *(const uint2*)p; hi = *(const uint2*)(p+4);
        } else {
          ushort t[8];
          #pragma unroll
          for (int i=0;i<8;i++) t[i] = (gr<Nc && gk+i<K) ? W[(size_t)gr*K + gk + i] : (ushort)0;
          lo = make_uint2(((uint)t[0])|((uint)t[1]<<16), ((uint)t[2])|((uint)t[3]<<16));
          hi = make_uint2(((uint)t[4])|((uint)t[5]<<16), ((uint)t[6])|((uint)t[7]<<16));
        }
        *(uint2*)&Bs[r*LDP + c]     = lo;
        *(uint2*)&Bs[r*LDP + c + 4] = hi;
      }
      if (MODE==7){ // second B tile
        int gr = col0 + r;
        uint2 lo, hi;
        if (gr < Nc && gk + 8 <= K){
          const ushort* p = W2 + (size_t)gr*K + gk;
          lo = *(const uint2*)p; hi = *(const uint2*)(p+4);
        } else {
          ushort t[8];
          #pragma unroll
          for (int i=0;i<8;i++) t[i] = (gr<Nc && gk+i<K) ? W2[(size_t)gr*K + gk + i] : (ushort)0;
          lo = make_uint2(((uint)t[0])|((uint)t[1]<<16), ((uint)t[2])|((uint)t[3]<<16));
          hi = make_uint2(((uint)t[4])|((uint)t[5]<<16), ((uint)t[6])|((uint)t[7]<<16));
        }
        *(uint2*)&Bs2[r*LDP + c]     = lo;
        *(uint2*)&Bs2[r*LDP + c + 4] = hi;
      }
    }
    __syncthreads();
    bf16x8 af[4], bfr[4];
    #pragma unroll
    for (int i=0;i<4;i++) af[i]  = *(const bf16x8*)&As[(wm + i*16 + lr)*LDP + lq*8];
    #pragma unroll
    for (int i=0;i<4;i++) bfr[i] = *(const bf16x8*)&Bs[(wn + i*16 + lr)*LDP + lq*8];
    #pragma unroll
    for (int i=0;i<4;i++)
      #pragma unroll
      for (int j=0;j<4;j++)
        acc[i][j] = __builtin_amdgcn_mfma_f32_16x16x32_bf16(af[i], bfr[j], acc[i][j], 0,0,0);
    if (MODE==7){
      bf16x8 bfr2[4];
      #pragma unroll
      for (int i=0;i<4;i++) bfr2[i] = *(const bf16x8*)&Bs2[(wn + i*16 + lr)*LDP + lq*8];
      #pragma unroll
      for (int i=0;i<4;i++)
        #pragma unroll
        for (int j=0;j<4;j++)
          acc2[i][j] = __builtin_amdgcn_mfma_f32_16x16x32_bf16(af[i], bfr2[j], acc2[i][j], 0,0,0);
    }
    __syncthreads();
  }

  const ushort* aux1b = (const ushort*)aux1;
  const float*  aux1f = (const float*)aux1;
  float* aux2f = (float*)aux2;

  #pragma unroll
  for (int i=0;i<4;i++){
    int rowb = row0 + wm + i*16 + lq*4;
    #pragma unroll
    for (int j=0;j<4;j++){
      int c = col0 + wn + j*16 + lr;
      float bv  = bias  ? bias[c]  : 0.0f;
      float bv2 = (MODE==7) ? bias2[c] : 0.0f;
      #pragma unroll
      for (int rg=0; rg<4; rg++){
        int row = rowb + rg;
        if (row < M){
          float vv = acc[i][j][rg] + bv;
          size_t idx = (size_t)row*Nc + c;
          if (MODE==0){
            ((ushort*)Cptr)[idx] = f2bf(vv);
          } else if (MODE==1){
            vv = vv/(1.0f + __expf(-vv));
            ((ushort*)Cptr)[idx] = f2bf(vv);
          } else if (MODE==4){
            aux2f[idx] *= vv;
          } else if (MODE==5){
            float r = aux1f[idx] + vv;
            ((float*)Cptr)[idx] = r;
          } else if (MODE==6){
            float o1 = bf2f(aux1b[(size_t)(row/3)*Nc + c]);
            float r = vv*o1 + aux2f[idx];
            ((float*)Cptr)[idx] = r;
          } else if (MODE==7){
            float vv2 = acc2[i][j][rg] + bv2;
            atomicAdd(aux2f + (size_t)(row/3)*Nc + c, vv*vv2);
          }
        }
      }
    }
  }
}

// ---------------- Edge kernel: one wave per edge, 2 channels/lane --------------
__global__ __launch_bounds__(256) void edge_kernel(
    int estart, int ecount,
    const int* __restrict__ ei, const float* __restrict__ rij,
    const float* __restrict__ dij,
    const ushort* __restrict__ q, const ushort* __restrict__ k,
    const ushort* __restrict__ v, const ushort* __restrict__ vecb,
    const ushort* __restrict__ dk, const ushort* __restrict__ dv,
    float* __restrict__ x_agg, float* __restrict__ vec_agg)
{
  int le = blockIdx.x*4 + (threadIdx.x>>6);
  if (le >= ecount) return;
  int e = estart + le;
  int lane = threadIdx.x & 63;
  int src = ei[e], dst = ei[N_EDGES + e];

  uint qp  = ((const uint*)q )[(size_t)dst*64 + lane];
  uint kp  = ((const uint*)k )[(size_t)src*64 + lane];
  uint dkp = ((const uint*)dk)[(size_t)le *64 + lane];
  float s = bflo(qp)*bflo(kp)*bflo(dkp) + bfhi(qp)*bfhi(kp)*bfhi(dkp);
  s += __shfl_xor(s,1); s += __shfl_xor(s,2); s += __shfl_xor(s,4);  // per-head (8 lanes)
  float r = rij[e];
  float cut = (r < 6.0f) ? 0.5f*(__cosf(r*0.52359877559829887f) + 1.0f) : 0.0f;
  float attn = (s/(1.0f + __expf(-s))) * cut;

  int h = lane>>3;
  int j0 = (2*lane) & 15;
  int cb = h*24 + (j0>>1);          // uint index within 3HD=48-ch head block
  size_t vr = (size_t)src*192, dvr = (size_t)le*192;
  const uint* v32  = (const uint*)v;
  const uint* dv32 = (const uint*)dv;
  uint vx = v32[vr+cb],    dvx = dv32[dvr+cb];
  uint v1 = v32[vr+cb+8],  dv1 = dv32[dvr+cb+8];
  uint v2 = v32[vr+cb+16], dv2 = dv32[dvr+cb+16];
  float xm0  = bflo(vx)*bflo(dvx)*attn, xm1  = bfhi(vx)*bfhi(dvx)*attn;
  float v1m0 = bflo(v1)*bflo(dv1),      v1m1 = bfhi(v1)*bfhi(dv1);
  float v2m0 = bflo(v2)*bflo(dv2),      v2m1 = bfhi(v2)*bfhi(dv2);

  int f0 = 2*lane;
  float* xrow = x_agg + (size_t)dst*128;
  atomicAdd(xrow + f0,     xm0);
  atomicAdd(xrow + f0 + 1, xm1);

  float d0 = dij[3*(size_t)e], d1 = dij[3*(size_t)e+1], d2 = dij[3*(size_t)e+2];
  float dxyz[3] = {d0, d1, d2};
  const uint* vec32 = (const uint*)vecb;
  float* vrow = vec_agg + (size_t)dst*384;
  #pragma unroll
  for (int a=0;a<3;a++){
    uint vv = vec32[(size_t)src*192 + a*64 + lane];
    float m0 = bflo(vv)*v1m0 + v2m0*dxyz[a];
    float m1 = bfhi(vv)*v1m1 + v2m1*dxyz[a];
    atomicAdd(vrow + a*128 + f0,     m0);
    atomicAdd(vrow + a*128 + f0 + 1, m1);
  }
}

extern "C" void kernel_launch(void* const* d_in, const int* in_sizes, int n_in,
                              void* d_out, int out_size, void* d_ws, size_t ws_size,
                              hipStream_t stream)
{
  (void)in_sizes; (void)n_in; (void)out_size;
  constexpr int Nn = N_NODES, Ee = N_EDGES;
  const float* x    = (const float*)d_in[0];
  const float* vec  = (const float*)d_in[1];
  const int*   eidx = (const int*)  d_in[2];
  const float* rij  = (const float*)d_in[3];
  const float* fij  = (const float*)d_in[4];
  const float* dij  = (const float*)d_in[5];
  const float* lnw  = (const float*)d_in[6];
  const float* lnb  = (const float*)d_in[7];
  const float* Wq   = (const float*)d_in[8];
  const float* bq   = (const float*)d_in[9];
  const float* Wk   = (const float*)d_in[10];
  const float* bk   = (const float*)d_in[11];
  const float* Wv   = (const float*)d_in[12];
  const float* bv   = (const float*)d_in[13];
  const float* Wvec = (const float*)d_in[14];
  const float* bvec = (const float*)d_in[15];
  const float* Wo   = (const float*)d_in[16];
  const float* bo   = (const float*)d_in[17];
  const float* Wdk  = (const float*)d_in[18];
  const float* bdk  = (const float*)d_in[19];
  const float* Wdv  = (const float*)d_in[20];
  const float* bdv  = (const float*)d_in[21];

  // ---- d_out (f32, 25.6M floats) time-multiplexing ----
  // [0 , 6.4M)  floats: qb(bf16)+kb(bf16) during edge phase -> vdot(f32) -> dx(f32)
  // [6.4M,25.6M) floats: vec_agg accumulator (f32) -> dvec (f32, same addresses)
  float*  outf = (float*)d_out;
  ushort* qb   = (ushort*)d_out;                    // 12.8 MB
  ushort* kb   = qb + (size_t)Nn*128;               // 12.8 MB
  float*  vdot = outf;                              // Nn*128 f32
  float*  vagg = outf + (size_t)Nn*128;             // 3*Nn*128 f32

  // ---- workspace ----
  char* w = (char*)d_ws;
  size_t off = 0;
  auto alloc = [&](size_t bytes){ size_t o = off; off += (bytes + 255) & ~(size_t)255; return o; };

  ushort* WqB   = (ushort*)(w + alloc(16384*2));
  ushort* WkB   = (ushort*)(w + alloc(16384*2));
  ushort* WvB   = (ushort*)(w + alloc(49152*2));
  ushort* WvecB = (ushort*)(w + alloc(49152*2));
  ushort* WoB   = (ushort*)(w + alloc(49152*2));
  ushort* WdkB  = (ushort*)(w + alloc(12800*2));
  ushort* WdvB  = (ushort*)(w + alloc(38400*2));
  ushort* vecb  = (ushort*)(w + alloc((size_t)3*Nn*128*2));  // 38.4 MB
  ushort* vb    = (ushort*)(w + alloc((size_t)Nn*384*2));    // 38.4 MB
  float*  xagg  = (float*) (w + alloc((size_t)Nn*128*4));    // 25.6 MB
  ushort* o1b   = (ushort*)(w + alloc((size_t)Nn*128*2));    // 12.8 MB

  // scratch: xn (12.8 MB) -> dk/dv edge chunks
  size_t sc_off = off;
  char*  sc = w + sc_off;
  ushort* xn = (ushort*)sc;
  long long chunkC = (ws_size > sc_off) ? (long long)((ws_size - sc_off) / 1024) : 64;
  if (chunkC > Ee) chunkC = Ee;
  chunkC &= ~63LL;
  if (chunkC < 64) chunkC = 64;
  ushort* dkc = (ushort*)sc;
  ushort* dvc = (ushort*)(sc + (size_t)chunkC*256);

  // ---- weight / vec conversion ----
  f32_to_bf16<<<(16384+255)/256, 256, 0, stream>>>(Wq,   WqB,   16384);
  f32_to_bf16<<<(16384+255)/256, 256, 0, stream>>>(Wk,   WkB,   16384);
  f32_to_bf16<<<(49152+255)/256, 256, 0, stream>>>(Wv,   WvB,   49152);
  f32_to_bf16<<<(49152+255)/256, 256, 0, stream>>>(Wvec, WvecB, 49152);
  f32_to_bf16<<<(49152+255)/256, 256, 0, stream>>>(Wo,   WoB,   49152);
  f32_to_bf16<<<(12800+255)/256, 256, 0, stream>>>(Wdk,  WdkB,  12800);
  f32_to_bf16<<<(38400+255)/256, 256, 0, stream>>>(Wdv,  WdvB,  38400);
  f32_to_bf16<<<(3*Nn*128+255)/256, 256, 0, stream>>>(vec, vecb, 3*Nn*128);

  hipMemsetAsync(xagg, 0, (size_t)Nn*128*4, stream);
  hipMemsetAsync(vagg, 0, (size_t)3*Nn*128*4, stream);

  ln_kernel<<<(Nn+3)/4, 256, 0, stream>>>(x, lnw, lnb, xn);

  gemm_bt<0,0><<<dim3((Nn+127)/128, 1), 256, 0, stream>>>(xn, WqB, nullptr, bq, nullptr, qb, nullptr, nullptr, Nn, 128, 128);
  gemm_bt<0,0><<<dim3((Nn+127)/128, 1), 256, 0, stream>>>(xn, WkB, nullptr, bk, nullptr, kb, nullptr, nullptr, Nn, 128, 128);
  gemm_bt<0,0><<<dim3((Nn+127)/128, 3), 256, 0, stream>>>(xn, WvB, nullptr, bv, nullptr, vb, nullptr, nullptr, Nn, 128, 384);

  // edge phase, chunked dk/dv (scratch reuses xn region; xn dead after v GEMM)
  for (int st = 0; st < Ee; st += (int)chunkC){
    int len = Ee - st; if (len > (int)chunkC) len = (int)chunkC;
    const float* fchunk = fij + (size_t)st*100;
    gemm_bt<1,1><<<dim3((len+127)/128, 1), 256, 0, stream>>>(fchunk, WdkB, nullptr, bdk, nullptr, dkc, nullptr, nullptr, len, 100, 128);
    gemm_bt<1,1><<<dim3((len+127)/128, 3), 256, 0, stream>>>(fchunk, WdvB, nullptr, bdv, nullptr, dvc, nullptr, nullptr, len, 100, 384);
    edge_kernel<<<(len+3)/4, 256, 0, stream>>>(st, len, eidx, rij, dij, qb, kb, vb, vecb, dkc, dvc, xagg, vagg);
  }

  // qb/kb dead; reuse dx region as f32 vdot accumulator
  hipMemsetAsync(vdot, 0, (size_t)Nn*128*4, stream);
  gemm_bt<7,0><<<dim3((3*Nn+127)/128, 1), 256, 0, stream>>>(vecb, WvecB, WvecB + 128*128, bvec, bvec + 128, nullptr, nullptr, vdot, 3*Nn, 128, 128);

  // o1 = xagg@Wo1^T+b ; vdot *= o2 ; dx = vdot + o3 ; dvec = vec3*o1 + vagg
  gemm_bt<0,1><<<dim3((Nn+127)/128, 1), 256, 0, stream>>>(xagg, WoB,            nullptr, bo,       nullptr, o1b,    nullptr, nullptr, Nn, 128, 128);
  gemm_bt<4,1><<<dim3((Nn+127)/128, 1), 256, 0, stream>>>(xagg, WoB + 128*128,  nullptr, bo + 128, nullptr, nullptr, nullptr, vdot,   Nn, 128, 128);
  gemm_bt<5,1><<<dim3((Nn+127)/128, 1), 256, 0, stream>>>(xagg, WoB + 256*128,  nullptr, bo + 256, nullptr, outf,   vdot,    nullptr, Nn, 128, 128);
  gemm_bt<6,0><<<dim3((3*Nn+127)/128, 1), 256, 0, stream>>>(vecb, WvecB + 256*128, nullptr, bvec + 256, nullptr, outf + (size_t)Nn*128, o1b, vagg, 3*Nn, 128, 128);
}